// Round 6
// baseline (221.123 us; speedup 1.0000x reference)
//
#include <hip/hip_runtime.h>
#include <cmath>

// Problem constants (fixed by the reference).
constexpr int B  = 4096;
constexpr int D  = 768;
constexpr int P  = 96;
constexpr int C  = 256;
constexpr int SD = 8;    // D / P

constexpr int TPB  = 256;   // 4 waves
constexpr int ROWS = 4;     // rows per lane
constexpr int CH2  = C / 2; // 128 centroids per wave (c-split x2)

// ---- numpy fp32 emulation helpers (exact path, validated absmax=0) ---------
__device__ __forceinline__ float tree8(float q0, float q1, float q2, float q3,
                                       float q4, float q5, float q6, float q7)
{
#pragma clang fp contract(off)
    return ((q0 + q1) + (q2 + q3)) + ((q4 + q5) + (q6 + q7));
}

__device__ __forceinline__ float proba_np(const float* __restrict__ cbf,
                                          const float* __restrict__ csq,
                                          int c, float4 va, float4 vb, float vsq)
{
#pragma clang fp contract(off)
    float4 ca = ((const float4*)cbf)[2 * c];
    float4 cb = ((const float4*)cbf)[2 * c + 1];
    float p0 = va.x * ca.x, p1 = va.y * ca.y, p2 = va.z * ca.z, p3 = va.w * ca.w;
    float p4 = vb.x * cb.x, p5 = vb.y * cb.y, p6 = vb.z * cb.z, p7 = vb.w * cb.w;
    float l0 = p0 + p4, l1 = p1 + p5, l2 = p2 + p6, l3 = p3 + p7;
    float vc = (l0 + l2) + (l1 + l3);
    float tt = vsq - 2.0f * vc;
    float u  = tt + csq[c];
    return -u;
}

// Exact numpy-order argmax incl. softmax tie path (validated rounds 1-5).
__device__ __attribute__((noinline))
int exact_search(const float* __restrict__ cbf, const float* __restrict__ csq,
                 float4 va, float4 vb, float vsq)
{
#pragma clang fp contract(off)
    float best = -3.402823466e38f, second = -3.402823466e38f;
    int bi = 0;
    for (int c = 0; c < C; ++c) {
        float pr = proba_np(cbf, csq, c, va, vb, vsq);
        if (pr > best)        { second = best; best = pr; bi = c; }
        else if (pr > second) { second = pr; }
    }
    int idx = bi;

    if (best - second <= 1.0e-6f) {
        float m = best;
        float r0[8] = {0,0,0,0,0,0,0,0};
        float r1[8] = {0,0,0,0,0,0,0,0};
        for (int cg = 0; cg < 16; ++cg) {
            #pragma unroll
            for (int j = 0; j < 8; ++j) {
                float pr = proba_np(cbf, csq, cg * 8 + j, va, vb, vsq);
                r0[j] += expf(pr - m);
            }
        }
        for (int cg = 16; cg < 32; ++cg) {
            #pragma unroll
            for (int j = 0; j < 8; ++j) {
                float pr = proba_np(cbf, csq, cg * 8 + j, va, vb, vsq);
                r1[j] += expf(pr - m);
            }
        }
        float sum = tree8(r0[0],r0[1],r0[2],r0[3],r0[4],r0[5],r0[6],r0[7])
                  + tree8(r1[0],r1[1],r1[2],r1[3],r1[4],r1[5],r1[6],r1[7]);
        float abest = -1.0f;
        int   ai    = 0;
        for (int c = 0; c < C; ++c) {
            float pr = proba_np(cbf, csq, c, va, vb, vsq);
            float e  = expf(pr - m);
            float a  = e / sum;
            if (a > abest) { abest = a; ai = c; }
        }
        idx = ai;
    }
    return idx;
}

// Block = 4 waves x 64 lanes = 2 partitions x 256 rows.
// Wave w: p_loc = w>>1, c_half = w&1 -> scores 128 centroids for 256 rows
// (4 rows/lane). Halves merged per row through LDS with ascending strict-'>'
// (== sequential first-index-wins scan; validated in round 4).
// LDS-pipe per wave: 128c -> 64 groups x (8 ds_read_b128 + 1 b128 for csqh).
__global__ __launch_bounds__(TPB, 3)
void pq_bal_kernel(const float* __restrict__ vecs,
                   const float* __restrict__ codebook,
                   float* __restrict__ out)
{
    __shared__ float  cbl [2 * C * SD];     // 16 KB: 2 partitions' codebooks
    __shared__ float  csqn[2 * C];          //  2 KB: ||c||^2 numpy order
    __shared__ float  csqh[2 * C];          //  2 KB: -0.5*csq (16B-aligned)
    __shared__ float2 part_bs[4][256];      //  8 KB: per-wave (best, second)
    __shared__ int    part_i [4][256];      //  4 KB: per-wave argmax

    const int t  = threadIdx.x;
    const int w  = t >> 6;
    const int l  = t & 63;
    const int p_loc  = w >> 1;             // 0..1 local partition
    const int c_half = w & 1;              // 0..1 centroid half
    const int bx = blockIdx.x;             // 0..47
    const int rowbase = blockIdx.y * 256;

    // ---- stage 2 codebooks: 4096 floats = 1024 float4, 4 per thread ----
    {
        const float4* src = (const float4*)(codebook + (size_t)(2 * bx) * C * SD);
        float4* dst = (float4*)cbl;
        #pragma unroll
        for (int k = 0; k < 4; ++k)
            dst[t + 256 * k] = src[t + 256 * k];
    }
    __syncthreads();

    // ---- csq (numpy order) + fast seed: 512 centroids, 2 per thread ----
    #pragma unroll
    for (int k = 0; k < 2; ++k) {
        int c = t + 256 * k;
        const float* cc = cbl + c * SD;
        float q0 = cc[0]*cc[0], q1 = cc[1]*cc[1], q2 = cc[2]*cc[2], q3 = cc[3]*cc[3];
        float q4 = cc[4]*cc[4], q5 = cc[5]*cc[5], q6 = cc[6]*cc[6], q7 = cc[7]*cc[7];
        float s = tree8(q0,q1,q2,q3,q4,q5,q6,q7);
        csqn[c] = s;
        csqh[c] = -0.5f * s;
    }
    __syncthreads();

    // ---- load this lane's 4 sub-vectors for partition p = 2*bx + p_loc ----
    const int p = 2 * bx + p_loc;
    float4 va[ROWS], vb[ROWS];
    #pragma unroll
    for (int r = 0; r < ROWS; ++r) {
        const float* vptr = vecs + (size_t)(rowbase + 64 * r + l) * D + (size_t)p * SD;
        va[r] = ((const float4*)vptr)[0];
        vb[r] = ((const float4*)vptr)[1];
    }

    // ---- fast scoring: 128 centroids, 4-wide register staging ----
    const float4* CB = (const float4*)(cbl + p_loc * C * SD);
    const float*  CH = csqh + p_loc * C;

    float best[ROWS], second[ROWS];
    int   bi[ROWS];
    #pragma unroll
    for (int r = 0; r < ROWS; ++r) {
        best[r] = -3.402823466e38f; second[r] = -3.402823466e38f; bi[r] = 0;
    }

    const int c0 = c_half * CH2;
    for (int c = c0; c < c0 + CH2; c += 4) {
        float4 A[4], Bv[4];
        #pragma unroll
        for (int u = 0; u < 4; ++u) {       // 8 broadcast b128 reads
            A[u]  = CB[2 * (c + u)];
            Bv[u] = CB[2 * (c + u) + 1];
        }
        float4 H4 = *(const float4*)(CH + c);  // 1 b128 for 4 csqh values
        float H[4] = { H4.x, H4.y, H4.z, H4.w };
        #pragma unroll
        for (int u = 0; u < 4; ++u) {
            #pragma unroll
            for (int r = 0; r < ROWS; ++r) {
                float s = fmaf(va[r].x, A[u].x, H[u]);
                s = fmaf(va[r].y, A[u].y, s);
                s = fmaf(va[r].z, A[u].z, s);
                s = fmaf(va[r].w, A[u].w, s);
                s = fmaf(vb[r].x, Bv[u].x, s);
                s = fmaf(vb[r].y, Bv[u].y, s);
                s = fmaf(vb[r].z, Bv[u].z, s);
                s = fmaf(vb[r].w, Bv[u].w, s);
                bool gt = s > best[r];
                second[r] = fmaxf(second[r], fminf(s, best[r]));
                bi[r]     = gt ? (c + u) : bi[r];
                best[r]   = fmaxf(s, best[r]);
            }
        }
    }

    // ---- publish partials (row-indexed) ----
    #pragma unroll
    for (int r = 0; r < ROWS; ++r) {
        part_bs[w][64 * r + l] = make_float2(best[r], second[r]);
        part_i [w][64 * r + l] = bi[r];
    }
    __syncthreads();

    // ---- merge halves + resolve + store: thread t handles row rowbase+t for
    //      both partitions (j = local partition) ----
    #pragma unroll
    for (int j = 0; j < 2; ++j) {
        float2 b0 = part_bs[2 * j][t];
        float2 b1 = part_bs[2 * j + 1][t];
        int    i0 = part_i [2 * j][t];
        int    i1 = part_i [2 * j + 1][t];

        // ascending c_half, strict '>' => first (smaller c) wins ties
        bool  gt  = b1.x > b0.x;
        float Bst = fmaxf(b0.x, b1.x);
        float Snd = fmaxf(fmaxf(b0.y, b1.y), fminf(b0.x, b1.x));
        int   I   = gt ? i1 : i0;

        const int row = rowbase + t;
        const int pj  = 2 * bx + j;
        int idx = I;
        if (Bst - Snd <= 2.0e-5f) {          // near-tie: exact numpy path
            const float* vptr = vecs + (size_t)row * D + (size_t)pj * SD;
            float4 xa = ((const float4*)vptr)[0];
            float4 xb = ((const float4*)vptr)[1];
            float q0 = xa.x*xa.x, q1 = xa.y*xa.y, q2 = xa.z*xa.z, q3 = xa.w*xa.w;
            float q4 = xb.x*xb.x, q5 = xb.y*xb.y, q6 = xb.z*xb.z, q7 = xb.w*xb.w;
            float vsq = tree8(q0,q1,q2,q3,q4,q5,q6,q7);
            idx = exact_search(cbl + j * C * SD, csqn + j * C, xa, xb, vsq);
        }

        const float4* cbw = (const float4*)(cbl + j * C * SD);
        float4 o0 = cbw[2 * idx];
        float4 o1 = cbw[2 * idx + 1];
        float4* op = (float4*)(out + (size_t)row * D + (size_t)pj * SD);
        op[0] = o0;
        op[1] = o1;
    }
}

extern "C" void kernel_launch(void* const* d_in, const int* in_sizes, int n_in,
                              void* d_out, int out_size, void* d_ws, size_t ws_size,
                              hipStream_t stream)
{
    const float* vecs     = (const float*)d_in[0];  // [B, D] fp32
    const float* codebook = (const float*)d_in[1];  // [P, C, SD] fp32
    float*       out      = (float*)d_out;          // [B, D] fp32

    dim3 grid(P / 2, B / 256);   // (48, 16) = 768 blocks -> 3 per CU
    dim3 block(TPB);
    pq_bal_kernel<<<grid, block, 0, stream>>>(vecs, codebook, out);
}

// Round 7
// 186.986 us; speedup vs baseline: 1.1826x; 1.1826x over previous
//
#include <hip/hip_runtime.h>
#include <cmath>

// Problem constants (fixed by the reference).
constexpr int B  = 4096;
constexpr int D  = 768;
constexpr int P  = 96;
constexpr int C  = 256;
constexpr int SD = 8;    // D / P

constexpr int TPB  = 128;   // 2 waves
constexpr int ROWS = 4;     // rows per thread -> block covers 512 rows

// ---- numpy fp32 emulation helpers (exact path, validated absmax=0) ---------
__device__ __forceinline__ float tree8(float q0, float q1, float q2, float q3,
                                       float q4, float q5, float q6, float q7)
{
#pragma clang fp contract(off)
    return ((q0 + q1) + (q2 + q3)) + ((q4 + q5) + (q6 + q7));
}

__device__ __forceinline__ float proba_np(const float* __restrict__ cbf,
                                          const float* __restrict__ csq,
                                          int c, float4 va, float4 vb, float vsq)
{
#pragma clang fp contract(off)
    float4 ca = ((const float4*)cbf)[2 * c];
    float4 cb = ((const float4*)cbf)[2 * c + 1];
    float p0 = va.x * ca.x, p1 = va.y * ca.y, p2 = va.z * ca.z, p3 = va.w * ca.w;
    float p4 = vb.x * cb.x, p5 = vb.y * cb.y, p6 = vb.z * cb.z, p7 = vb.w * cb.w;
    float l0 = p0 + p4, l1 = p1 + p5, l2 = p2 + p6, l3 = p3 + p7;
    float vc = (l0 + l2) + (l1 + l3);
    float tt = vsq - 2.0f * vc;
    float u  = tt + csq[c];
    return -u;
}

// Exact numpy-order argmax incl. softmax tie path (validated rounds 1-6).
__device__ __attribute__((noinline))
int exact_search(const float* __restrict__ cbf, const float* __restrict__ csq,
                 float4 va, float4 vb, float vsq)
{
#pragma clang fp contract(off)
    float best = -3.402823466e38f, second = -3.402823466e38f;
    int bi = 0;
    for (int c = 0; c < C; ++c) {
        float pr = proba_np(cbf, csq, c, va, vb, vsq);
        if (pr > best)        { second = best; best = pr; bi = c; }
        else if (pr > second) { second = pr; }
    }
    int idx = bi;

    if (best - second <= 1.0e-6f) {
        float m = best;
        float r0[8] = {0,0,0,0,0,0,0,0};
        float r1[8] = {0,0,0,0,0,0,0,0};
        for (int cg = 0; cg < 16; ++cg) {
            #pragma unroll
            for (int j = 0; j < 8; ++j) {
                float pr = proba_np(cbf, csq, cg * 8 + j, va, vb, vsq);
                r0[j] += expf(pr - m);
            }
        }
        for (int cg = 16; cg < 32; ++cg) {
            #pragma unroll
            for (int j = 0; j < 8; ++j) {
                float pr = proba_np(cbf, csq, cg * 8 + j, va, vb, vsq);
                r1[j] += expf(pr - m);
            }
        }
        float sum = tree8(r0[0],r0[1],r0[2],r0[3],r0[4],r0[5],r0[6],r0[7])
                  + tree8(r1[0],r1[1],r1[2],r1[3],r1[4],r1[5],r1[6],r1[7]);
        float abest = -1.0f;
        int   ai    = 0;
        for (int c = 0; c < C; ++c) {
            float pr = proba_np(cbf, csq, c, va, vb, vsq);
            float e  = expf(pr - m);
            float a  = e / sum;
            if (a > abest) { abest = a; ai = c; }
        }
        idx = ai;
    }
    return idx;
}

// Block = 128 threads (2 waves) x ROWS=4 -> 512 rows, one partition p.
// INNER LOOP READS CENTROIDS FROM GLOBAL with wave-uniform addresses
// (scalar/broadcast path, L2-resident 8KB) + manual next-group prefetch.
// LDS is setup-only: csqh seeds (1 b128 per 4-centroid group) and a codebook
// copy used only by the rare exact path and the final per-lane gather.
__global__ __launch_bounds__(TPB, 3)
void pq_smem_kernel(const float* __restrict__ vecs,
                    const float* __restrict__ codebook,
                    float* __restrict__ out)
{
    __shared__ float cbf [C * SD];  // 8 KB (exact path + gather only)
    __shared__ float csqn[C];       // 1 KB numpy-order ||c||^2 (exact path)
    __shared__ float csqh[C];       // 1 KB -0.5*csq (fast seeds, b128-read)

    const int p = blockIdx.x;                 // 0..95
    const int t = threadIdx.x;                // 0..127
    const int rowbase = blockIdx.y * (TPB * ROWS);

    // ---- issue this thread's 4 sub-vector loads first (longest latency) ----
    float4 va[ROWS], vb[ROWS];
    #pragma unroll
    for (int r = 0; r < ROWS; ++r) {
        const float* vptr = vecs + (size_t)(rowbase + TPB * r + t) * D + (size_t)p * SD;
        va[r] = ((const float4*)vptr)[0];
        vb[r] = ((const float4*)vptr)[1];
    }

    // ---- stage codebook[p] into LDS (for exact path + gather) ----
    const float4* CBg = (const float4*)(codebook + (size_t)p * C * SD);
    #pragma unroll
    for (int k = 0; k < 4; ++k)
        ((float4*)cbf)[t + TPB * k] = CBg[t + TPB * k];
    __syncthreads();

    // ---- csq (numpy order) + fast seed: 2 centroids per thread ----
    #pragma unroll
    for (int k = 0; k < 2; ++k) {
        int c = t + TPB * k;
        const float* cc = cbf + c * SD;
        float q0 = cc[0]*cc[0], q1 = cc[1]*cc[1], q2 = cc[2]*cc[2], q3 = cc[3]*cc[3];
        float q4 = cc[4]*cc[4], q5 = cc[5]*cc[5], q6 = cc[6]*cc[6], q7 = cc[7]*cc[7];
        float s = tree8(q0,q1,q2,q3,q4,q5,q6,q7);
        csqn[c] = s;
        csqh[c] = -0.5f * s;
    }
    __syncthreads();

    // ---- fast scan: 64 groups of 4 centroids, global-uniform loads,
    //      next-group software prefetch ----
    float best[ROWS], second[ROWS];
    int   bi[ROWS];
    #pragma unroll
    for (int r = 0; r < ROWS; ++r) {
        best[r] = -3.402823466e38f; second[r] = -3.402823466e38f; bi[r] = 0;
    }

    float4 A[8], N[8];
    #pragma unroll
    for (int i = 0; i < 8; ++i) A[i] = CBg[i];   // group 0

    for (int g = 0; g < 64; ++g) {
        const int gn = (g + 1) & 63;             // wraps to 0 on last iter
        #pragma unroll
        for (int i = 0; i < 8; ++i) N[i] = CBg[8 * gn + i];  // prefetch

        float4 H4 = ((const float4*)csqh)[g];    // 4 seeds, one b128
        float  H[4] = { H4.x, H4.y, H4.z, H4.w };

        #pragma unroll
        for (int u = 0; u < 4; ++u) {
            const float4 ca = A[2 * u];
            const float4 cb = A[2 * u + 1];
            #pragma unroll
            for (int r = 0; r < ROWS; ++r) {
                float s = fmaf(va[r].x, ca.x, H[u]);
                s = fmaf(va[r].y, ca.y, s);
                s = fmaf(va[r].z, ca.z, s);
                s = fmaf(va[r].w, ca.w, s);
                s = fmaf(vb[r].x, cb.x, s);
                s = fmaf(vb[r].y, cb.y, s);
                s = fmaf(vb[r].z, cb.z, s);
                s = fmaf(vb[r].w, cb.w, s);
                bool gt = s > best[r];
                second[r] = fmaxf(second[r], fminf(s, best[r]));
                bi[r]     = gt ? (4 * g + u) : bi[r];
                best[r]   = fmaxf(s, best[r]);
            }
        }
        #pragma unroll
        for (int i = 0; i < 8; ++i) A[i] = N[i];
    }

    // ---- resolve (rare exact path) + gather + store ----
    #pragma unroll
    for (int r = 0; r < ROWS; ++r) {
        int idx = bi[r];
        if (best[r] - second[r] <= 2.0e-5f) {    // near-tie: exact numpy path
            float q0 = va[r].x*va[r].x, q1 = va[r].y*va[r].y,
                  q2 = va[r].z*va[r].z, q3 = va[r].w*va[r].w;
            float q4 = vb[r].x*vb[r].x, q5 = vb[r].y*vb[r].y,
                  q6 = vb[r].z*vb[r].z, q7 = vb[r].w*vb[r].w;
            float vsq = tree8(q0,q1,q2,q3,q4,q5,q6,q7);
            idx = exact_search(cbf, csqn, va[r], vb[r], vsq);
        }
        float4 o0 = ((const float4*)cbf)[2 * idx];
        float4 o1 = ((const float4*)cbf)[2 * idx + 1];
        float4* op = (float4*)(out + (size_t)(rowbase + TPB * r + t) * D + (size_t)p * SD);
        op[0] = o0;
        op[1] = o1;
    }
}

extern "C" void kernel_launch(void* const* d_in, const int* in_sizes, int n_in,
                              void* d_out, int out_size, void* d_ws, size_t ws_size,
                              hipStream_t stream)
{
    const float* vecs     = (const float*)d_in[0];  // [B, D] fp32
    const float* codebook = (const float*)d_in[1];  // [P, C, SD] fp32
    float*       out      = (float*)d_out;          // [B, D] fp32

    dim3 grid(P, B / (TPB * ROWS));   // (96, 8) = 768 blocks -> 3 per CU
    dim3 block(TPB);
    pq_smem_kernel<<<grid, block, 0, stream>>>(vecs, codebook, out);
}

// Round 8
// 178.023 us; speedup vs baseline: 1.2421x; 1.0503x over previous
//
#include <hip/hip_runtime.h>
#include <cmath>

// Problem constants (fixed by the reference).
constexpr int B  = 4096;
constexpr int D  = 768;
constexpr int P  = 96;
constexpr int C  = 256;
constexpr int SD = 8;    // D / P

constexpr int TPB  = 256;   // 4 waves
constexpr int ROWS = 2;     // rows per lane -> 128 rows per block
constexpr int CPW  = C / 4; // 64 centroids per wave

// ---- numpy fp32 emulation helpers (exact path, validated absmax=0) ---------
__device__ __forceinline__ float tree8(float q0, float q1, float q2, float q3,
                                       float q4, float q5, float q6, float q7)
{
#pragma clang fp contract(off)
    return ((q0 + q1) + (q2 + q3)) + ((q4 + q5) + (q6 + q7));
}

__device__ __forceinline__ float proba_np(const float* __restrict__ cbf,
                                          const float* __restrict__ csq,
                                          int c, float4 va, float4 vb, float vsq)
{
#pragma clang fp contract(off)
    float4 ca = ((const float4*)cbf)[2 * c];
    float4 cb = ((const float4*)cbf)[2 * c + 1];
    float p0 = va.x * ca.x, p1 = va.y * ca.y, p2 = va.z * ca.z, p3 = va.w * ca.w;
    float p4 = vb.x * cb.x, p5 = vb.y * cb.y, p6 = vb.z * cb.z, p7 = vb.w * cb.w;
    float l0 = p0 + p4, l1 = p1 + p5, l2 = p2 + p6, l3 = p3 + p7;
    float vc = (l0 + l2) + (l1 + l3);
    float tt = vsq - 2.0f * vc;
    float u  = tt + csq[c];
    return -u;
}

// Exact numpy-order argmax incl. softmax tie path (validated rounds 1-7).
__device__ __attribute__((noinline))
int exact_search(const float* __restrict__ cbf, const float* __restrict__ csq,
                 float4 va, float4 vb, float vsq)
{
#pragma clang fp contract(off)
    float best = -3.402823466e38f, second = -3.402823466e38f;
    int bi = 0;
    for (int c = 0; c < C; ++c) {
        float pr = proba_np(cbf, csq, c, va, vb, vsq);
        if (pr > best)        { second = best; best = pr; bi = c; }
        else if (pr > second) { second = pr; }
    }
    int idx = bi;

    if (best - second <= 1.0e-6f) {
        float m = best;
        float r0[8] = {0,0,0,0,0,0,0,0};
        float r1[8] = {0,0,0,0,0,0,0,0};
        for (int cg = 0; cg < 16; ++cg) {
            #pragma unroll
            for (int j = 0; j < 8; ++j) {
                float pr = proba_np(cbf, csq, cg * 8 + j, va, vb, vsq);
                r0[j] += expf(pr - m);
            }
        }
        for (int cg = 16; cg < 32; ++cg) {
            #pragma unroll
            for (int j = 0; j < 8; ++j) {
                float pr = proba_np(cbf, csq, cg * 8 + j, va, vb, vsq);
                r1[j] += expf(pr - m);
            }
        }
        float sum = tree8(r0[0],r0[1],r0[2],r0[3],r0[4],r0[5],r0[6],r0[7])
                  + tree8(r1[0],r1[1],r1[2],r1[3],r1[4],r1[5],r1[6],r1[7]);
        float abest = -1.0f;
        int   ai    = 0;
        for (int c = 0; c < C; ++c) {
            float pr = proba_np(cbf, csq, c, va, vb, vsq);
            float e  = expf(pr - m);
            float a  = e / sum;
            if (a > abest) { abest = a; ai = c; }
        }
        idx = ai;
    }
    return idx;
}

// Max-TLP variant: block = 4 waves x 64 lanes covers 128 rows x 1 partition.
// Wave w scores centroid quarter [64w, 64w+64) for all 128 rows (2 rows/lane).
// Grid (96, 32) = 3072 blocks = 12288 waves -> ~32 resident waves per CU
// (the HW cap), 16 KB LDS/block. Quarters merged per row with the
// round-4-validated ascending strict-'>' merge (numpy first-index-wins).
__global__ __launch_bounds__(TPB, 6)
void pq_occ_kernel(const float* __restrict__ vecs,
                   const float* __restrict__ codebook,
                   float* __restrict__ out)
{
    __shared__ float  cbf [C * SD];      // 8 KB codebook[p]
    __shared__ float  csqn[C];           // 1 KB ||c||^2 numpy order (exact path)
    __shared__ float  csqh[C];           // 1 KB -0.5*csq (fast seeds)
    __shared__ float2 part_bs[4][128];   // 4 KB per-quarter (best, second)
    __shared__ int    part_i [4][128];   // 2 KB per-quarter argmax

    const int p = blockIdx.x;                 // 0..95
    const int t = threadIdx.x;
    const int w = t >> 6;                     // wave id = centroid quarter
    const int l = t & 63;
    const int rowbase = blockIdx.y * 128;

    // ---- stage codebook[p]: 512 float4, 2 per thread ----
    const float4* src = (const float4*)(codebook + (size_t)p * C * SD);
    ((float4*)cbf)[t]       = src[t];
    ((float4*)cbf)[t + 256] = src[t + 256];
    __syncthreads();

    // ---- csq (numpy order) + fast seed: 1 centroid per thread ----
    {
        const float* cc = cbf + t * SD;
        float q0 = cc[0]*cc[0], q1 = cc[1]*cc[1], q2 = cc[2]*cc[2], q3 = cc[3]*cc[3];
        float q4 = cc[4]*cc[4], q5 = cc[5]*cc[5], q6 = cc[6]*cc[6], q7 = cc[7]*cc[7];
        float s = tree8(q0,q1,q2,q3,q4,q5,q6,q7);
        csqn[t] = s;
        csqh[t] = -0.5f * s;
    }
    __syncthreads();

    // ---- load this lane's 2 sub-vectors (same rows in all 4 waves -> L1) ----
    float4 va[ROWS], vb[ROWS];
    #pragma unroll
    for (int r = 0; r < ROWS; ++r) {
        const float* vptr = vecs + (size_t)(rowbase + 64 * r + l) * D + (size_t)p * SD;
        va[r] = ((const float4*)vptr)[0];
        vb[r] = ((const float4*)vptr)[1];
    }

    // ---- fast scoring: 64 centroids (this wave's quarter), 4-wide staging ----
    float best[ROWS], second[ROWS];
    int   bi[ROWS];
    #pragma unroll
    for (int r = 0; r < ROWS; ++r) {
        best[r] = -3.402823466e38f; second[r] = -3.402823466e38f; bi[r] = 0;
    }

    const int c0 = w * CPW;
    for (int c = c0; c < c0 + CPW; c += 4) {
        float4 A[4], Bv[4];
        #pragma unroll
        for (int u = 0; u < 4; ++u) {          // 8 broadcast b128 reads
            A[u]  = ((const float4*)cbf)[2 * (c + u)];
            Bv[u] = ((const float4*)cbf)[2 * (c + u) + 1];
        }
        float4 H4 = *(const float4*)(csqh + c);  // 4 seeds, one b128
        float  H[4] = { H4.x, H4.y, H4.z, H4.w };
        #pragma unroll
        for (int u = 0; u < 4; ++u) {
            #pragma unroll
            for (int r = 0; r < ROWS; ++r) {
                float s = fmaf(va[r].x, A[u].x, H[u]);
                s = fmaf(va[r].y, A[u].y, s);
                s = fmaf(va[r].z, A[u].z, s);
                s = fmaf(va[r].w, A[u].w, s);
                s = fmaf(vb[r].x, Bv[u].x, s);
                s = fmaf(vb[r].y, Bv[u].y, s);
                s = fmaf(vb[r].z, Bv[u].z, s);
                s = fmaf(vb[r].w, Bv[u].w, s);
                bool gt = s > best[r];
                second[r] = fmaxf(second[r], fminf(s, best[r]));
                bi[r]     = gt ? (c + u) : bi[r];
                best[r]   = fmaxf(s, best[r]);
            }
        }
    }

    // ---- publish quarter partials (row-indexed) ----
    #pragma unroll
    for (int r = 0; r < ROWS; ++r) {
        part_bs[w][64 * r + l] = make_float2(best[r], second[r]);
        part_i [w][64 * r + l] = bi[r];
    }
    __syncthreads();

    // ---- merge + resolve + store: threads 0..127, one row each ----
    if (t < 128) {
        float Bst = -3.402823466e38f, Snd = -3.402823466e38f;
        int   I   = 0;
        #pragma unroll
        for (int q = 0; q < 4; ++q) {          // ascending quarters, strict '>'
            float2 bs = part_bs[q][t];
            int    iq = part_i [q][t];
            bool gt = bs.x > Bst;
            Snd = fmaxf(Snd, fminf(bs.x, Bst));
            Snd = fmaxf(Snd, bs.y);
            I   = gt ? iq : I;
            Bst = fmaxf(Bst, bs.x);
        }

        const int row = rowbase + t;
        int idx = I;
        if (Bst - Snd <= 2.0e-5f) {            // near-tie: exact numpy path
            const float* vptr = vecs + (size_t)row * D + (size_t)p * SD;
            float4 xa = ((const float4*)vptr)[0];
            float4 xb = ((const float4*)vptr)[1];
            float q0 = xa.x*xa.x, q1 = xa.y*xa.y, q2 = xa.z*xa.z, q3 = xa.w*xa.w;
            float q4 = xb.x*xb.x, q5 = xb.y*xb.y, q6 = xb.z*xb.z, q7 = xb.w*xb.w;
            float vsq = tree8(q0,q1,q2,q3,q4,q5,q6,q7);
            idx = exact_search(cbf, csqn, xa, xb, vsq);
        }

        float4 o0 = ((const float4*)cbf)[2 * idx];
        float4 o1 = ((const float4*)cbf)[2 * idx + 1];
        float4* op = (float4*)(out + (size_t)row * D + (size_t)p * SD);
        op[0] = o0;
        op[1] = o1;
    }
}

extern "C" void kernel_launch(void* const* d_in, const int* in_sizes, int n_in,
                              void* d_out, int out_size, void* d_ws, size_t ws_size,
                              hipStream_t stream)
{
    const float* vecs     = (const float*)d_in[0];  // [B, D] fp32
    const float* codebook = (const float*)d_in[1];  // [P, C, SD] fp32
    float*       out      = (float*)d_out;          // [B, D] fp32

    dim3 grid(P, B / 128);   // (96, 32) = 3072 blocks = 12288 waves
    dim3 block(TPB);
    pq_occ_kernel<<<grid, block, 0, stream>>>(vecs, codebook, out);
}